// Round 15
// baseline (451.884 us; speedup 1.0000x reference)
//
#include <hip/hip_runtime.h>

// Problem constants
#define B_ 4
#define S_ 2048
#define D_ 1024
#define H_ 16
#define HD_ 64
#define F_ 4096
#define M_ (B_*S_)   // 8192 tokens
#define QS_ 3072     // fused QKV row stride

// dtypes (established r2-r6): d_in = float32, d_out = float32.

typedef __attribute__((ext_vector_type(8))) short bf16x8;   // 8 bf16 (4 VGPR) MFMA A/B frag
typedef __attribute__((ext_vector_type(4))) short short4_t; // 4 bf16 (8B)
typedef __attribute__((ext_vector_type(4))) float f32x4;    // 16x16 MFMA C/D frag
typedef __attribute__((ext_vector_type(16))) float f32x16;  // 32x32 MFMA C/D frag

#define AS1q __attribute__((address_space(1)))
#define AS3q __attribute__((address_space(3)))

__device__ __forceinline__ float bf2f(short u) {
    union { unsigned int i; float f; } v;
    v.i = ((unsigned int)(unsigned short)u) << 16;
    return v.f;
}
__device__ __forceinline__ short f2bf(float f) {
    union { float f; unsigned int i; } v; v.f = f;
    unsigned int r = v.i + 0x7fffu + ((v.i >> 16) & 1u);  // RNE
    return (short)(r >> 16);
}
__device__ __forceinline__ void gld_lds16(const short* g, short* l) {
    __builtin_amdgcn_global_load_lds((const AS1q void*)g, (AS3q void*)l, 16, 0, 0);
}
__device__ __forceinline__ unsigned int cvtpk_bf16(float a, float b) {
    unsigned int r;
    asm("v_cvt_pk_bf16_f32 %0, %1, %2" : "=v"(r) : "v"(a), "v"(b));
    return r;
}
__device__ __forceinline__ float max3f(float a, float b, float c) {
    float r;
    asm("v_max3_f32 %0, %1, %2, %3" : "=v"(r) : "v"(a), "v"(b), "v"(c));
    return r;
}

// ---------------------------------------------------------------------------
// fp32 -> bf16 convert (grid-stride, float4 loads)
// ---------------------------------------------------------------------------
__global__ __launch_bounds__(256) void cvt_f2b_k(
    const float* __restrict__ in, short* __restrict__ out, long n)
{
    long i = ((long)blockIdx.x * 256 + threadIdx.x) * 4;
    long stride = (long)gridDim.x * 256 * 4;
    for (; i < n; i += stride) {
        float4 v = *(const float4*)(in + i);
        short4_t o;
        o[0] = f2bf(v.x); o[1] = f2bf(v.y); o[2] = f2bf(v.z); o[3] = f2bf(v.w);
        *(short4_t*)(out + i) = o;
    }
}

// ---------------------------------------------------------------------------
// Tiled transpose: out[z][c][r] = cvt(in[base(z) + r*in_rstride + c])
// ---------------------------------------------------------------------------
template<typename TI>
__global__ __launch_bounds__(256) void transpose_k(
    const TI* __restrict__ in, short* __restrict__ out,
    int rows, long in_rstride,
    long in_bstrideB, long in_bstrideH, long out_bstride)
{
    __shared__ short tile[32][33];
    int z = blockIdx.z;
    const TI* ip = in + (long)(z >> 4) * in_bstrideB + (long)(z & 15) * in_bstrideH;
    short* op = out + (long)z * out_bstride;
    int r0 = blockIdx.y * 32, c0 = blockIdx.x * 32;
    int tx = threadIdx.x & 31, ty = threadIdx.x >> 5;   // ty 0..7
#pragma unroll
    for (int i = 0; i < 32; i += 8) {
        TI v = ip[(long)(r0 + ty + i) * in_rstride + (c0 + tx)];
        if constexpr (sizeof(TI) == 4) tile[ty + i][tx] = f2bf((float)v);
        else                           tile[ty + i][tx] = (short)v;
    }
    __syncthreads();
#pragma unroll
    for (int i = 0; i < 32; i += 8)
        op[(long)(c0 + ty + i) * rows + (r0 + tx)] = tile[tx][ty + i];
}

// ---------------------------------------------------------------------------
// GEMM 128x128 (m97 structure + XCD swizzle + 2-phase prefetch) — used for
// N=1024 outputs (Wo, FFN2) where a 256^2 grid would leave half the CUs idle.
// ---------------------------------------------------------------------------
__global__ __launch_bounds__(256) void gemm_k(
    const short* __restrict__ A,    // [M][K] bf16
    const short* __restrict__ BT,   // [N][K] bf16
    const float* __restrict__ bias, // [N] fp32
    short* __restrict__ C,          // [M][N] bf16
    int M, int N, int K, float scale, int relu)
{
    __shared__ short Alds[2*128*32];   // double-buffered, linear
    __shared__ short Blds[2*128*32];
    int tid = threadIdx.x;
    int wave = tid >> 6, lane = tid & 63;
    int lgrp = lane >> 4, lrow = lane & 15;
    int wr = wave >> 1, wc = wave & 1;
    int gx = gridDim.x;
    int nwg = gx * gridDim.y;
    int lin = blockIdx.y * gx + blockIdx.x;
    int nid = (lin & 7) * (nwg >> 3) + (lin >> 3);
    int bm = (nid / gx) * 128, bn = (nid % gx) * 128;

    int srow = wave * 32 + (lane >> 2);
    int scol = (lane & 3) * 8;
    const short* gA = A  + (long)(bm + srow) * K + scol;
    const short* gB = BT + (long)(bn + srow) * K + scol;
    short* lA0 = &Alds[(wave * 32) * 32];
    short* lA1 = &Alds[(wave * 32 + 16) * 32];
    short* lB0 = &Blds[(wave * 32) * 32];
    short* lB1 = &Blds[(wave * 32 + 16) * 32];
    long k16 = 16L * K;

    #define GSTAGE(buf, k0_) do {                              \
        gld_lds16(gA + (k0_),       lA0 + (buf)*4096);         \
        gld_lds16(gA + (k0_) + k16, lA1 + (buf)*4096);         \
        gld_lds16(gB + (k0_),       lB0 + (buf)*4096);         \
        gld_lds16(gB + (k0_) + k16, lB1 + (buf)*4096);         \
    } while (0)

    f32x4 acc[4][4] = {};
    int nk = K >> 5;
    GSTAGE(0, 0);
    __syncthreads();
    for (int t = 0; t < nk; ++t) {
        int cur = t & 1;
        if (t + 1 < nk) GSTAGE(cur ^ 1, (t + 1) * 32);   // overlaps MFMA below
        bf16x8 af[4], bv[4];
#pragma unroll
        for (int i = 0; i < 4; i++) {
            af[i] = *(const bf16x8*)&Alds[cur*4096 + (wr*64 + i*16 + lrow) * 32 + 8*lgrp];
            bv[i] = *(const bf16x8*)&Blds[cur*4096 + (wc*64 + i*16 + lrow) * 32 + 8*lgrp];
        }
#pragma unroll
        for (int mi = 0; mi < 4; mi++)
#pragma unroll
            for (int ni = 0; ni < 4; ni++)
                acc[mi][ni] = __builtin_amdgcn_mfma_f32_16x16x32_bf16(
                    af[mi], bv[ni], acc[mi][ni], 0, 0, 0);
        __syncthreads();   // drains prefetch (vmcnt) + orders buf reuse
    }
    #undef GSTAGE
#pragma unroll
    for (int ni = 0; ni < 4; ni++) {
        int col = bn + wc*64 + ni*16 + lrow;
        float bb = bias[col];
#pragma unroll
        for (int mi = 0; mi < 4; mi++) {
#pragma unroll
            for (int j = 0; j < 4; j++) {
                int row = bm + wr*64 + mi*16 + lgrp*4 + j;
                float v = (acc[mi][ni][j] + bb) * scale;
                if (relu) v = fmaxf(v, 0.0f);
                C[(long)row * N + col] = f2bf(v);
            }
        }
    }
}

// ---------------------------------------------------------------------------
// GEMM 256x256, BK=32, 8 waves (512 thr), 4-slot LDS ring, COUNTED vmcnt(4):
// stage runs 2 K-tiles ahead via global_load_lds; raw s_barrier (no drain);
// one barrier + one vmcnt per K-step. LDS read swizzle: chunk ^= (row>>1)&3
// (2-way conflict = free) with matching pre-swizzled global source chunks
// (both-sides rule; same pattern as attn's staging since r11).
// Ledger: 4 loads/wave/tile, FIFO; at tile-t top outstanding<=8, vmcnt(4)
// => tile t landed; barrier publishes cross-wave; slot (t+2)&3 dead (read
// at t-2, barrier-separated). Dummy clamped stages keep ledger uniform;
// vmcnt(0) after loop prevents stale landings into a successor block's LDS.
// MODE: 0 = plain C=[M][N] (+relu); 1 = fused QKV (Q scale, V->VT transposed).
// ---------------------------------------------------------------------------
template<int MODE>
__global__ __launch_bounds__(512, 2) void gemm256_k(
    const short* __restrict__ A,     // [M][K] bf16
    const short* __restrict__ BT,    // [N][K] bf16
    const float* __restrict__ bias,  // MODE0: [N]
    const float* __restrict__ bk,    // MODE1: bq=bias, bk, bv
    const float* __restrict__ bv,
    short* __restrict__ C,           // MODE0: [M][N]; MODE1: [M][3072]
    short* __restrict__ VT,          // MODE1: [64][64][2048]
    int M, int N, int K, float scale, int relu)
{
    __shared__ short Al[4][256*32];   // ring of 4 K-steps, [256 rows][32 k]
    __shared__ short Bl[4][256*32];
    int tid = threadIdx.x;
    int wave = tid >> 6, lane = tid & 63;
    int lgrp = lane >> 4, lrow = lane & 15;
    int wr = wave >> 2, wc = wave & 3;     // 2 x 4 wave grid; out 128x64/wave
    int gx = gridDim.x;
    int nwg = gx * gridDim.y;
    int lin = blockIdx.y * gx + blockIdx.x;
    int nid = (lin & 7) * (nwg >> 3) + (lin >> 3);
    int bm = (nid / gx) * 256, bn = (nid % gx) * 256;

    // staging: wave w instr j covers rows w*32+j*16..+16; lane l ->
    // LDS (row base+(l>>2), chunk l&3) linear; source chunk (l&3)^((l>>3)&3)
    int srow = lane >> 2;                      // 0..15
    int schunk = (lane & 3) ^ ((lane >> 3) & 3);
    const short* gA0 = A  + (long)(bm + wave*32 + srow) * K + schunk*8;
    const short* gA1 = gA0 + 16L*K;
    const short* gB0 = BT + (long)(bn + wave*32 + srow) * K + schunk*8;
    const short* gB1 = gB0 + 16L*K;
    short* lA = &Al[0][(wave*32)*32];
    short* lB = &Bl[0][(wave*32)*32];

    #define G256(slot, k0_) do {                         \
        gld_lds16(gA0 + (k0_), lA + (slot)*8192);         \
        gld_lds16(gA1 + (k0_), lA + (slot)*8192 + 512);   \
        gld_lds16(gB0 + (k0_), lB + (slot)*8192);         \
        gld_lds16(gB1 + (k0_), lB + (slot)*8192 + 512);   \
    } while (0)

    f32x4 acc[8][4] = {};
    int nk = K >> 5;
    G256(0, 0);
    G256(1, 32);
    for (int t = 0; t < nk; ++t) {
        int cur = t & 3;
        asm volatile("s_waitcnt vmcnt(4)" ::: "memory");  // tile t landed (this wave)
        __builtin_amdgcn_s_barrier();                      // publish across waves
        __builtin_amdgcn_sched_barrier(0);
        // stage tile t+2 (clamped dummy at tail keeps vmcnt ledger uniform)
        {
            int ts = (t + 2 < nk) ? (t + 2) : (nk - 1);
            G256((t + 2) & 3, ts * 32);
        }
        const short* Ab = &Al[cur][0];
        const short* Bb = &Bl[cur][0];
        bf16x8 bfr[4];
#pragma unroll
        for (int ni = 0; ni < 4; ni++) {
            int row = wc*64 + ni*16 + lrow;
            bfr[ni] = *(const bf16x8*)(Bb + row*32 + ((lgrp ^ ((row >> 1) & 3)) << 3));
        }
#pragma unroll
        for (int half = 0; half < 2; half++) {
            bf16x8 afr[4];
#pragma unroll
            for (int i = 0; i < 4; i++) {
                int row = wr*128 + (half*4 + i)*16 + lrow;
                afr[i] = *(const bf16x8*)(Ab + row*32 + ((lgrp ^ ((row >> 1) & 3)) << 3));
            }
            __builtin_amdgcn_s_setprio(1);
#pragma unroll
            for (int i = 0; i < 4; i++)
#pragma unroll
                for (int ni = 0; ni < 4; ni++)
                    acc[half*4 + i][ni] = __builtin_amdgcn_mfma_f32_16x16x32_bf16(
                        afr[i], bfr[ni], acc[half*4 + i][ni], 0, 0, 0);
            __builtin_amdgcn_s_setprio(0);
        }
    }
    #undef G256
    asm volatile("s_waitcnt vmcnt(0)" ::: "memory");  // drain dummies before endpgm

    if constexpr (MODE == 1) {
        int seg = bn >> 10;                    // 0=Q 1=K 2=V (block-uniform)
        const float* bp = (seg == 0) ? bias : (seg == 1) ? bk : bv;
        float qs = (seg == 0) ? scale : 1.0f;
        if (seg == 2) {
            int bq0 = bm >> 11;                // batch
#pragma unroll
            for (int ni = 0; ni < 4; ni++) {
                int col = bn + wc*64 + ni*16 + lrow;
                int e   = col & 63;
                int bh  = bq0*16 + ((col >> 6) - 32);
                float bb = bp[col & 1023];
#pragma unroll
                for (int mi = 0; mi < 8; mi++) {
                    int tok = (bm + wr*128 + mi*16 + lgrp*4) & 2047;
                    short4_t o;
#pragma unroll
                    for (int j = 0; j < 4; j++) o[j] = f2bf(acc[mi][ni][j] + bb);
                    *(short4_t*)(VT + (long)bh*131072L + (long)e*2048 + tok) = o;
                }
            }
        } else {
#pragma unroll
            for (int ni = 0; ni < 4; ni++) {
                int col = bn + wc*64 + ni*16 + lrow;
                float bb = bp[col & 1023];
#pragma unroll
                for (int mi = 0; mi < 8; mi++) {
#pragma unroll
                    for (int j = 0; j < 4; j++) {
                        int row = bm + wr*128 + mi*16 + lgrp*4 + j;
                        C[(long)row * QS_ + col] = f2bf((acc[mi][ni][j] + bb) * qs);
                    }
                }
            }
        }
    } else {
#pragma unroll
        for (int ni = 0; ni < 4; ni++) {
            int col = bn + wc*64 + ni*16 + lrow;
            float bb = bias[col];
#pragma unroll
            for (int mi = 0; mi < 8; mi++) {
#pragma unroll
                for (int j = 0; j < 4; j++) {
                    int row = bm + wr*128 + mi*16 + lgrp*4 + j;
                    float v = acc[mi][ni][j] + bb;
                    if (relu) v = fmaxf(v, 0.0f);
                    C[(long)row * N + col] = f2bf(v);
                }
            }
        }
    }
}

// ---------------------------------------------------------------------------
// Flash attention v8 (unchanged from r14).
// ---------------------------------------------------------------------------
__global__ __launch_bounds__(256) void attn_k(
    const short* __restrict__ QKV,  // [M][3072]: Q|K segs, Q scaled
    const short* __restrict__ VT,   // [64][64][2048]
    short* __restrict__ O)          // [M][1024]
{
    __shared__ short KV[2][2][4096];   // [buf][K/V][64 rows x 64 shorts] = 32KB
    int lin = blockIdx.y * 16 + blockIdx.x;
    int nid = (lin & 7) * 128 + (lin >> 3);
    int bh = nid >> 4, qt = nid & 15;
    int b = bh >> 4, h = bh & 15;
    int q0 = qt * 128;
    int tid = threadIdx.x, wave = tid >> 6, lane = tid & 63;
    int l31 = lane & 31, hi = lane >> 5;
    int sw = l31 & 7;                        // read-side XOR swizzle key

    bf16x8 aq[4];
    {
        const short* qp = QKV + (long)(b*S_ + q0 + wave*32 + l31) * QS_ + h*64 + 8*hi;
#pragma unroll
        for (int t = 0; t < 4; t++)
            aq[t] = *(const bf16x8*)(qp + 16*t);
    }
    bf16x8 ones;
#pragma unroll
    for (int i = 0; i < 8; i++) ones[i] = (short)0x3F80;

    f32x16 accO[2] = {};           // O[qrow=crow(r,hi)][e=32eb+l31]
    f32x16 accsum = {};            // row sums (all cols equal)
    float negmj = 0.0f;            // -(running max), exp2 domain

    int srow = lane >> 3;                    // 0..7
    int schunk = (lane & 7) ^ srow;          // 16B chunk index
    const short* ksrc = QKV + (long)(b*S_ + wave*16 + srow) * QS_ + 1024 + h*64 + schunk*8;
    const short* vsrc = VT + (long)bh * (64L*S_) + (long)(wave*16 + srow) * S_ + schunk*8;
    short* kd = &KV[0][0][wave*1024];
    short* vd = &KV[0][1][wave*1024];

    #define STAGE(buf, kb_) do {                                        \
        gld_lds16(ksrc + (long)(kb_)     * QS_, kd + (buf)*8192);        \
        gld_lds16(ksrc + (long)((kb_)+8) * QS_, kd + (buf)*8192 + 512);  \
        gld_lds16(vsrc + (kb_),                 vd + (buf)*8192);        \
        gld_lds16(vsrc + 8*S_ + (kb_),          vd + (buf)*8192 + 512);  \
    } while (0)

    STAGE(0, 0);
    __syncthreads();

    for (int t = 0; t < 32; ++t) {
        int cur = t & 1;
        if (t < 31) STAGE(cur ^ 1, (t + 1) * 64);
        const char* KB = (const char*)&KV[cur][0][0];
        const char* VB = (const char*)&KV[cur][1][0];

        // ---- QK^T with C-init = -mj: accs = s - mj after MFMA ----
        f32x16 accs[2];
#pragma unroll
        for (int c = 0; c < 2; c++)
#pragma unroll
            for (int r = 0; r < 16; r++) accs[c][r] = negmj;
#pragma unroll
        for (int c = 0; c < 2; c++) {
            bf16x8 ak[4];
#pragma unroll
            for (int tt = 0; tt < 4; tt++)
                ak[tt] = *(const bf16x8*)(KB + (32*c + l31)*128 + (((2*tt + hi) ^ sw) << 4));
            __builtin_amdgcn_s_setprio(1);
#pragma unroll
            for (int tt = 0; tt < 4; tt++)
                accs[c] = __builtin_amdgcn_mfma_f32_32x32x16_bf16(
                    ak[tt], aq[tt], accs[c], 0, 0, 0);
            __builtin_amdgcn_s_setprio(0);
        }

        // ---- defer-max guard, every 4th tile only ----
        if ((t & 3) == 0) {
            float mA = fmaxf(accs[0][0], accs[0][1]);
            float mB = fmaxf(accs[1][0], accs[1][1]);
#pragma unroll
            for (int r = 2; r < 16; r += 2) {
                mA = max3f(mA, accs[0][r], accs[0][r+1]);
                mB = max3f(mB, accs[1][r], accs[1][r+1]);
            }
            float m4 = fmaxf(mA, mB);
            if (!__all(m4 <= 8.0f)) {          // rare rescale path
                float m2 = fmaxf(m4, __shfl_xor(m4, 32));
                float d = fmaxf(m2, 0.0f);
                float al = exp2f(-d);
                negmj -= d;
#pragma unroll
                for (int c = 0; c < 2; c++)
#pragma unroll
                    for (int r = 0; r < 16; r++) accs[c][r] -= d;
#pragma unroll
                for (int r = 0; r < 16; r++) {
                    float alr = __shfl(al, (r & 3) + 8 * (r >> 2) + 4 * hi);
                    accO[0][r] *= alr; accO[1][r] *= alr; accsum[r] *= alr;
                }
            }
        }
#pragma unroll
        for (int c = 0; c < 2; c++)
#pragma unroll
            for (int r = 0; r < 16; r++)
                accs[c][r] = exp2f(accs[c][r]);

        // ---- P -> A-frags: 4 cvt_pk + 2 permlane32_swap per 16-key slot ----
        bf16x8 pa[4];
#pragma unroll
        for (int ks = 0; ks < 4; ks++) {
            int c = ks >> 1, o = (ks & 1) * 8;
            unsigned int c0 = cvtpk_bf16(accs[c][o+0], accs[c][o+1]);
            unsigned int c1 = cvtpk_bf16(accs[c][o+2], accs[c][o+3]);
            unsigned int c2 = cvtpk_bf16(accs[c][o+4], accs[c][o+5]);
            unsigned int c3 = cvtpk_bf16(accs[c][o+6], accs[c][o+7]);
            asm("v_permlane32_swap_b32 %0, %1" : "+v"(c0), "+v"(c2));
            asm("v_permlane32_swap_b32 %0, %1" : "+v"(c1), "+v"(c3));
            union { unsigned int u[4]; bf16x8 v; } pk;
            pk.u[0] = c0; pk.u[1] = c1; pk.u[2] = c2; pk.u[3] = c3;
            pa[ks] = pk.v;
        }

        // ---- PV + MFMA row-sum ----
        __builtin_amdgcn_s_setprio(1);
#pragma unroll
        for (int eb = 0; eb < 2; eb++)
#pragma unroll
            for (int ks = 0; ks < 4; ks++) {
                bf16x8 bvf = *(const bf16x8*)(VB + (32*eb + l31)*128 + (((2*ks + hi) ^ sw) << 4));
                accO[eb] = __builtin_amdgcn_mfma_f32_32x32x16_bf16(
                    pa[ks], bvf, accO[eb], 0, 0, 0);
            }
#pragma unroll
        for (int ks = 0; ks < 4; ks++)
            accsum = __builtin_amdgcn_mfma_f32_32x32x16_bf16(
                pa[ks], ones, accsum, 0, 0, 0);
        __builtin_amdgcn_s_setprio(0);

        __syncthreads();
    }
    #undef STAGE

    const short* ob = O + (long)(b*S_) * 1024 + h*64;
#pragma unroll
    for (int r = 0; r < 16; r++) {
        int crow = (r & 3) + 8 * (r >> 2) + 4 * hi;
        float invr = 1.0f / accsum[r];
        int qr = q0 + wave*32 + crow;
#pragma unroll
        for (int eb = 0; eb < 2; eb++)
            ((short*)ob)[(long)qr * 1024 + 32*eb + l31] = f2bf(accO[eb][r] * invr);
    }
}

// ---------------------------------------------------------------------------
// Residual + LayerNorm: O[row] = LN(X[row] + Y[row]) * g + be   (D=1024)
// ---------------------------------------------------------------------------
template<int XF32, int OUTF32>
__global__ __launch_bounds__(256) void ln_k(
    const void* __restrict__ Xv, const short* __restrict__ Y,
    const float* __restrict__ g, const float* __restrict__ be,
    void* __restrict__ Ov)
{
    int row = blockIdx.x, tid = threadIdx.x;
    long base = (long)row * 1024 + tid * 4;
    float a[4];
    if constexpr (XF32) {
        float4 xv = *(const float4*)((const float*)Xv + base);
        a[0] = xv.x; a[1] = xv.y; a[2] = xv.z; a[3] = xv.w;
    } else {
        short4_t xv = *(const short4_t*)((const short*)Xv + base);
#pragma unroll
        for (int j = 0; j < 4; j++) a[j] = bf2f(xv[j]);
    }
    short4_t yv = *(const short4_t*)(Y + base);
    float s = 0.f, s2 = 0.f;
#pragma unroll
    for (int j = 0; j < 4; j++) {
        a[j] += bf2f(yv[j]);
        s += a[j]; s2 += a[j] * a[j];
    }
#pragma unroll
    for (int off = 32; off >= 1; off >>= 1) {
        s  += __shfl_xor(s, off);
        s2 += __shfl_xor(s2, off);
    }
    __shared__ float red[8];
    if ((tid & 63) == 0) { red[(tid >> 6)*2] = s; red[(tid >> 6)*2 + 1] = s2; }
    __syncthreads();
    s  = red[0] + red[2] + red[4] + red[6];
    s2 = red[1] + red[3] + red[5] + red[7];
    float mean = s * (1.0f/1024.0f);
    float var  = s2 * (1.0f/1024.0f) - mean*mean;
    float rstd = rsqrtf(var + 1e-5f);
    float4 gv = *(const float4*)(g  + tid*4);
    float4 bv = *(const float4*)(be + tid*4);
    float r0 = (a[0] - mean) * rstd * gv.x + bv.x;
    float r1 = (a[1] - mean) * rstd * gv.y + bv.y;
    float r2 = (a[2] - mean) * rstd * gv.z + bv.z;
    float r3 = (a[3] - mean) * rstd * gv.w + bv.w;
    if constexpr (OUTF32) {
        *(float4*)((float*)Ov + base) = make_float4(r0, r1, r2, r3);
    } else {
        short4_t ov;
        ov[0] = f2bf(r0); ov[1] = f2bf(r1); ov[2] = f2bf(r2); ov[3] = f2bf(r3);
        *(short4_t*)((short*)Ov + base) = ov;
    }
}

// ---------------------------------------------------------------------------
extern "C" void kernel_launch(void* const* d_in, const int* in_sizes, int n_in,
                              void* d_out, int out_size, void* d_ws, size_t ws_size,
                              hipStream_t stream)
{
    static const int ins[17] = {0,1,2,3,4,5,6,7,8,9,10,11,12,13,14,15,16};
    static const int srt[17] = {16,4,12,2,10,5,13,3,11,0,6,1,7,14,8,15,9};
    const int* IX = (in_sizes[0] == 8388608) ? ins : srt;

    const float* x   = (const float*)d_in[IX[0]];
    const float* Wq  = (const float*)d_in[IX[1]];
    const float* bq  = (const float*)d_in[IX[2]];
    const float* Wk  = (const float*)d_in[IX[3]];
    const float* bk  = (const float*)d_in[IX[4]];
    const float* Wv  = (const float*)d_in[IX[5]];
    const float* bv  = (const float*)d_in[IX[6]];
    const float* Wo  = (const float*)d_in[IX[7]];
    const float* bo  = (const float*)d_in[IX[8]];
    const float* W1  = (const float*)d_in[IX[9]];
    const float* b1  = (const float*)d_in[IX[10]];
    const float* W2  = (const float*)d_in[IX[11]];
    const float* b2  = (const float*)d_in[IX[12]];
    const float* g1  = (const float*)d_in[IX[13]];
    const float* be1 = (const float*)d_in[IX[14]];
    const float* g2  = (const float*)d_in[IX[15]];
    const float* be2 = (const float*)d_in[IX[16]];
    short* ws  = (short*)d_ws;

    // Workspace overlay (short offsets). Peak 125.8 MB.
    short* QKVb = ws + 0L;          // [8192][3072], dead after attn
    short* VTb  = ws + 25165824L;   // [64][64][2048], dead after attn
    short* ctx  = ws + 33554432L;   // [8192][1024], dead after Wo gemm
    short* QKVT = ws + 41943040L;   // [3072][1024], dead after QKV gemm
    short* WoT  = ws + 45088768L;   // [1024][1024], dead after Wo gemm
    short* xb   = ws + 46137344L;   // [8192][1024], dead after QKV gemm
    short* W1T  = ws + 54525952L;   // [4096][1024]
    short* W2T  = ws + 58720256L;   // [1024][4096]
    short* x1   = ws + 0L;          // reuses QKVb head (dead)
    short* hb   = ws + 8388608L;    // [8192][4096] reuses QKVb tail+VTb+ctx (dead)
    short* ao   = ws + 46137344L;   // reuses xb (dead)
    short* ffn  = ws + 41943040L;   // reuses QKVT+WoT (dead by FFN2)

    dim3 blk(256);

    cvt_f2b_k<<<2048, blk, 0, stream>>>(x, xb, (long)M_ * D_);

    // weight transposes (fp32 -> bf16), [N][K] k-contiguous
    transpose_k<float><<<dim3(2, 32, 16),  blk, 0, stream>>>(Wq, QKVT,            1024, 64,   0, 65536, 65536);
    transpose_k<float><<<dim3(2, 32, 16),  blk, 0, stream>>>(Wk, QKVT + 1048576L, 1024, 64,   0, 65536, 65536);
    transpose_k<float><<<dim3(2, 32, 16),  blk, 0, stream>>>(Wv, QKVT + 2097152L, 1024, 64,   0, 65536, 65536);
    transpose_k<float><<<dim3(32, 32, 1),  blk, 0, stream>>>(Wo, WoT, 1024, 1024, 0, 0, 0);
    transpose_k<float><<<dim3(128, 32, 1), blk, 0, stream>>>(W1, W1T, 1024, 4096, 0, 0, 0);
    transpose_k<float><<<dim3(32, 128, 1), blk, 0, stream>>>(W2, W2T, 4096, 1024, 0, 0, 0);

    // fused QKV projection, 256^2 counted-vmcnt kernel (V written transposed);
    // Q folds 0.125*log2(e) for exp2-domain softmax
    gemm256_k<1><<<dim3(12, 32), dim3(512), 0, stream>>>(
        xb, QKVT, bq, bk, bv, QKVb, VTb, M_, QS_, 1024, 0.18033688011112042f, 0);

    // flash attention
    attn_k<<<dim3(16, 64), blk, 0, stream>>>(QKVb, VTb, ctx);

    // out projection + residual LN (residual from ORIGINAL fp32 x)
    gemm_k<<<dim3(8, 64), blk, 0, stream>>>(ctx, WoT, bo, ao, M_, 1024, 1024, 1.0f, 0);
    ln_k<1,0><<<8192, blk, 0, stream>>>(x, ao, g1, be1, x1);

    // FFN1 on the 256^2 counted-vmcnt kernel (relu fused)
    gemm256_k<0><<<dim3(16, 32), dim3(512), 0, stream>>>(
        x1, W1T, b1, nullptr, nullptr, hb, nullptr, M_, 4096, 1024, 1.0f, 1);
    gemm_k<<<dim3(8, 64),  blk, 0, stream>>>(hb, W2T, b2, ffn, M_, 1024, 4096, 1.0f, 0);

    ln_k<0,1><<<8192, blk, 0, stream>>>(x1, ffn, g2, be2, d_out);
}

// Round 16
// 449.955 us; speedup vs baseline: 1.0043x; 1.0043x over previous
//
#include <hip/hip_runtime.h>

// Problem constants
#define B_ 4
#define S_ 2048
#define D_ 1024
#define H_ 16
#define HD_ 64
#define F_ 4096
#define M_ (B_*S_)   // 8192 tokens
#define QS_ 3072     // fused QKV row stride

// dtypes (established r2-r6): d_in = float32, d_out = float32.

typedef __attribute__((ext_vector_type(8))) short bf16x8;   // 8 bf16 (4 VGPR) MFMA A/B frag
typedef __attribute__((ext_vector_type(4))) short short4_t; // 4 bf16 (8B)
typedef __attribute__((ext_vector_type(4))) float f32x4;    // 16x16 MFMA C/D frag
typedef __attribute__((ext_vector_type(16))) float f32x16;  // 32x32 MFMA C/D frag

#define AS1q __attribute__((address_space(1)))
#define AS3q __attribute__((address_space(3)))

__device__ __forceinline__ float bf2f(short u) {
    union { unsigned int i; float f; } v;
    v.i = ((unsigned int)(unsigned short)u) << 16;
    return v.f;
}
__device__ __forceinline__ short f2bf(float f) {
    union { float f; unsigned int i; } v; v.f = f;
    unsigned int r = v.i + 0x7fffu + ((v.i >> 16) & 1u);  // RNE
    return (short)(r >> 16);
}
__device__ __forceinline__ void gld_lds16(const short* g, short* l) {
    __builtin_amdgcn_global_load_lds((const AS1q void*)g, (AS3q void*)l, 16, 0, 0);
}
__device__ __forceinline__ unsigned int cvtpk_bf16(float a, float b) {
    unsigned int r;
    asm("v_cvt_pk_bf16_f32 %0, %1, %2" : "=v"(r) : "v"(a), "v"(b));
    return r;
}
__device__ __forceinline__ float max3f(float a, float b, float c) {
    float r;
    asm("v_max3_f32 %0, %1, %2, %3" : "=v"(r) : "v"(a), "v"(b), "v"(c));
    return r;
}

// ---------------------------------------------------------------------------
// fp32 -> bf16 convert (grid-stride, float4 loads)
// ---------------------------------------------------------------------------
__global__ __launch_bounds__(256) void cvt_f2b_k(
    const float* __restrict__ in, short* __restrict__ out, long n)
{
    long i = ((long)blockIdx.x * 256 + threadIdx.x) * 4;
    long stride = (long)gridDim.x * 256 * 4;
    for (; i < n; i += stride) {
        float4 v = *(const float4*)(in + i);
        short4_t o;
        o[0] = f2bf(v.x); o[1] = f2bf(v.y); o[2] = f2bf(v.z); o[3] = f2bf(v.w);
        *(short4_t*)(out + i) = o;
    }
}

// ---------------------------------------------------------------------------
// Tiled transpose: out[z][c][r] = cvt(in[base(z) + r*in_rstride + c])
// ---------------------------------------------------------------------------
template<typename TI>
__global__ __launch_bounds__(256) void transpose_k(
    const TI* __restrict__ in, short* __restrict__ out,
    int rows, long in_rstride,
    long in_bstrideB, long in_bstrideH, long out_bstride)
{
    __shared__ short tile[32][33];
    int z = blockIdx.z;
    const TI* ip = in + (long)(z >> 4) * in_bstrideB + (long)(z & 15) * in_bstrideH;
    short* op = out + (long)z * out_bstride;
    int r0 = blockIdx.y * 32, c0 = blockIdx.x * 32;
    int tx = threadIdx.x & 31, ty = threadIdx.x >> 5;   // ty 0..7
#pragma unroll
    for (int i = 0; i < 32; i += 8) {
        TI v = ip[(long)(r0 + ty + i) * in_rstride + (c0 + tx)];
        if constexpr (sizeof(TI) == 4) tile[ty + i][tx] = f2bf((float)v);
        else                           tile[ty + i][tx] = (short)v;
    }
    __syncthreads();
#pragma unroll
    for (int i = 0; i < 32; i += 8)
        op[(long)(c0 + ty + i) * rows + (r0 + tx)] = tile[tx][ty + i];
}

// ---------------------------------------------------------------------------
// GEMM 128x128 (m97 structure + XCD swizzle + 2-phase prefetch) — used for
// N=1024 outputs (Wo, FFN2) where a 256^2 grid would leave half the CUs idle.
// ---------------------------------------------------------------------------
__global__ __launch_bounds__(256) void gemm_k(
    const short* __restrict__ A,    // [M][K] bf16
    const short* __restrict__ BT,   // [N][K] bf16
    const float* __restrict__ bias, // [N] fp32
    short* __restrict__ C,          // [M][N] bf16
    int M, int N, int K, float scale, int relu)
{
    __shared__ short Alds[2*128*32];   // double-buffered, linear
    __shared__ short Blds[2*128*32];
    int tid = threadIdx.x;
    int wave = tid >> 6, lane = tid & 63;
    int lgrp = lane >> 4, lrow = lane & 15;
    int wr = wave >> 1, wc = wave & 1;
    int gx = gridDim.x;
    int nwg = gx * gridDim.y;
    int lin = blockIdx.y * gx + blockIdx.x;
    int nid = (lin & 7) * (nwg >> 3) + (lin >> 3);
    int bm = (nid / gx) * 128, bn = (nid % gx) * 128;

    int srow = wave * 32 + (lane >> 2);
    int scol = (lane & 3) * 8;
    const short* gA = A  + (long)(bm + srow) * K + scol;
    const short* gB = BT + (long)(bn + srow) * K + scol;
    short* lA0 = &Alds[(wave * 32) * 32];
    short* lA1 = &Alds[(wave * 32 + 16) * 32];
    short* lB0 = &Blds[(wave * 32) * 32];
    short* lB1 = &Blds[(wave * 32 + 16) * 32];
    long k16 = 16L * K;

    #define GSTAGE(buf, k0_) do {                              \
        gld_lds16(gA + (k0_),       lA0 + (buf)*4096);         \
        gld_lds16(gA + (k0_) + k16, lA1 + (buf)*4096);         \
        gld_lds16(gB + (k0_),       lB0 + (buf)*4096);         \
        gld_lds16(gB + (k0_) + k16, lB1 + (buf)*4096);         \
    } while (0)

    f32x4 acc[4][4] = {};
    int nk = K >> 5;
    GSTAGE(0, 0);
    __syncthreads();
    for (int t = 0; t < nk; ++t) {
        int cur = t & 1;
        if (t + 1 < nk) GSTAGE(cur ^ 1, (t + 1) * 32);   // overlaps MFMA below
        bf16x8 af[4], bv[4];
#pragma unroll
        for (int i = 0; i < 4; i++) {
            af[i] = *(const bf16x8*)&Alds[cur*4096 + (wr*64 + i*16 + lrow) * 32 + 8*lgrp];
            bv[i] = *(const bf16x8*)&Blds[cur*4096 + (wc*64 + i*16 + lrow) * 32 + 8*lgrp];
        }
#pragma unroll
        for (int mi = 0; mi < 4; mi++)
#pragma unroll
            for (int ni = 0; ni < 4; ni++)
                acc[mi][ni] = __builtin_amdgcn_mfma_f32_16x16x32_bf16(
                    af[mi], bv[ni], acc[mi][ni], 0, 0, 0);
        __syncthreads();   // drains prefetch (vmcnt) + orders buf reuse
    }
    #undef GSTAGE
#pragma unroll
    for (int ni = 0; ni < 4; ni++) {
        int col = bn + wc*64 + ni*16 + lrow;
        float bb = bias[col];
#pragma unroll
        for (int mi = 0; mi < 4; mi++) {
#pragma unroll
            for (int j = 0; j < 4; j++) {
                int row = bm + wr*64 + mi*16 + lgrp*4 + j;
                float v = (acc[mi][ni][j] + bb) * scale;
                if (relu) v = fmaxf(v, 0.0f);
                C[(long)row * N + col] = f2bf(v);
            }
        }
    }
}

// ---------------------------------------------------------------------------
// GEMM 256x256, BK=32, 8 waves (512 thr), 4-slot LDS ring, COUNTED vmcnt(4):
// stage runs 2 K-tiles ahead via global_load_lds; raw s_barrier (no drain);
// one barrier + one vmcnt per K-step. LDS read swizzle: chunk ^= (row>>1)&3
// (2-way conflict = free) with matching pre-swizzled global source chunks
// (both-sides rule; same pattern as attn's staging since r11).
// Ledger: 4 loads/wave/tile, FIFO; at tile-t top outstanding<=8, vmcnt(4)
// => tile t landed; barrier publishes cross-wave; slot (t+2)&3 dead (read
// at t-2, barrier-separated). Dummy clamped stages keep ledger uniform;
// vmcnt(0) after loop prevents stale landings into a successor block's LDS.
// MODE: 0 = plain C=[M][N] (+relu); 1 = fused QKV (Q scale, V->VT transposed).
// ---------------------------------------------------------------------------
template<int MODE>
__global__ __launch_bounds__(512, 2) void gemm256_k(
    const short* __restrict__ A,     // [M][K] bf16
    const short* __restrict__ BT,    // [N][K] bf16
    const float* __restrict__ bias,  // MODE0: [N]
    const float* __restrict__ bk,    // MODE1: bq=bias, bk, bv
    const float* __restrict__ bv,
    short* __restrict__ C,           // MODE0: [M][N]; MODE1: [M][3072]
    short* __restrict__ VT,          // MODE1: [64][64][2048]
    int M, int N, int K, float scale, int relu)
{
    __shared__ short Al[4][256*32];   // ring of 4 K-steps, [256 rows][32 k]
    __shared__ short Bl[4][256*32];
    int tid = threadIdx.x;
    int wave = tid >> 6, lane = tid & 63;
    int lgrp = lane >> 4, lrow = lane & 15;
    int wr = wave >> 2, wc = wave & 3;     // 2 x 4 wave grid; out 128x64/wave
    int gx = gridDim.x;
    int nwg = gx * gridDim.y;
    int lin = blockIdx.y * gx + blockIdx.x;
    int nid = (lin & 7) * (nwg >> 3) + (lin >> 3);
    int bm = (nid / gx) * 256, bn = (nid % gx) * 256;

    // staging: wave w instr j covers rows w*32+j*16..+16; lane l ->
    // LDS (row base+(l>>2), chunk l&3) linear; source chunk (l&3)^((l>>3)&3)
    int srow = lane >> 2;                      // 0..15
    int schunk = (lane & 3) ^ ((lane >> 3) & 3);
    const short* gA0 = A  + (long)(bm + wave*32 + srow) * K + schunk*8;
    const short* gA1 = gA0 + 16L*K;
    const short* gB0 = BT + (long)(bn + wave*32 + srow) * K + schunk*8;
    const short* gB1 = gB0 + 16L*K;
    short* lA = &Al[0][(wave*32)*32];
    short* lB = &Bl[0][(wave*32)*32];

    #define G256(slot, k0_) do {                         \
        gld_lds16(gA0 + (k0_), lA + (slot)*8192);         \
        gld_lds16(gA1 + (k0_), lA + (slot)*8192 + 512);   \
        gld_lds16(gB0 + (k0_), lB + (slot)*8192);         \
        gld_lds16(gB1 + (k0_), lB + (slot)*8192 + 512);   \
    } while (0)

    f32x4 acc[8][4] = {};
    int nk = K >> 5;
    G256(0, 0);
    G256(1, 32);
    for (int t = 0; t < nk; ++t) {
        int cur = t & 3;
        asm volatile("s_waitcnt vmcnt(4)" ::: "memory");  // tile t landed (this wave)
        __builtin_amdgcn_s_barrier();                      // publish across waves
        __builtin_amdgcn_sched_barrier(0);
        // stage tile t+2 (clamped dummy at tail keeps vmcnt ledger uniform)
        {
            int ts = (t + 2 < nk) ? (t + 2) : (nk - 1);
            G256((t + 2) & 3, ts * 32);
        }
        const short* Ab = &Al[cur][0];
        const short* Bb = &Bl[cur][0];
        bf16x8 bfr[4];
#pragma unroll
        for (int ni = 0; ni < 4; ni++) {
            int row = wc*64 + ni*16 + lrow;
            bfr[ni] = *(const bf16x8*)(Bb + row*32 + ((lgrp ^ ((row >> 1) & 3)) << 3));
        }
#pragma unroll
        for (int half = 0; half < 2; half++) {
            bf16x8 afr[4];
#pragma unroll
            for (int i = 0; i < 4; i++) {
                int row = wr*128 + (half*4 + i)*16 + lrow;
                afr[i] = *(const bf16x8*)(Ab + row*32 + ((lgrp ^ ((row >> 1) & 3)) << 3));
            }
            __builtin_amdgcn_s_setprio(1);
#pragma unroll
            for (int i = 0; i < 4; i++)
#pragma unroll
                for (int ni = 0; ni < 4; ni++)
                    acc[half*4 + i][ni] = __builtin_amdgcn_mfma_f32_16x16x32_bf16(
                        afr[i], bfr[ni], acc[half*4 + i][ni], 0, 0, 0);
            __builtin_amdgcn_s_setprio(0);
        }
    }
    #undef G256
    asm volatile("s_waitcnt vmcnt(0)" ::: "memory");  // drain dummies before endpgm

    if constexpr (MODE == 1) {
        int seg = bn >> 10;                    // 0=Q 1=K 2=V (block-uniform)
        const float* bp = (seg == 0) ? bias : (seg == 1) ? bk : bv;
        float qs = (seg == 0) ? scale : 1.0f;
        if (seg == 2) {
            int bq0 = bm >> 11;                // batch
#pragma unroll
            for (int ni = 0; ni < 4; ni++) {
                int col = bn + wc*64 + ni*16 + lrow;
                int e   = col & 63;
                int bh  = bq0*16 + ((col >> 6) - 32);
                float bb = bp[col & 1023];
#pragma unroll
                for (int mi = 0; mi < 8; mi++) {
                    int tok = (bm + wr*128 + mi*16 + lgrp*4) & 2047;
                    short4_t o;
#pragma unroll
                    for (int j = 0; j < 4; j++) o[j] = f2bf(acc[mi][ni][j] + bb);
                    *(short4_t*)(VT + (long)bh*131072L + (long)e*2048 + tok) = o;
                }
            }
        } else {
#pragma unroll
            for (int ni = 0; ni < 4; ni++) {
                int col = bn + wc*64 + ni*16 + lrow;
                float bb = bp[col & 1023];
#pragma unroll
                for (int mi = 0; mi < 8; mi++) {
#pragma unroll
                    for (int j = 0; j < 4; j++) {
                        int row = bm + wr*128 + mi*16 + lgrp*4 + j;
                        C[(long)row * QS_ + col] = f2bf((acc[mi][ni][j] + bb) * qs);
                    }
                }
            }
        }
    } else {
#pragma unroll
        for (int ni = 0; ni < 4; ni++) {
            int col = bn + wc*64 + ni*16 + lrow;
            float bb = bias[col];
#pragma unroll
            for (int mi = 0; mi < 8; mi++) {
#pragma unroll
                for (int j = 0; j < 4; j++) {
                    int row = bm + wr*128 + mi*16 + lgrp*4 + j;
                    float v = acc[mi][ni][j] + bb;
                    if (relu) v = fmaxf(v, 0.0f);
                    C[(long)row * N + col] = f2bf(v);
                }
            }
        }
    }
}

// ---------------------------------------------------------------------------
// Flash attention v8 (unchanged from r14).
// ---------------------------------------------------------------------------
__global__ __launch_bounds__(256) void attn_k(
    const short* __restrict__ QKV,  // [M][3072]: Q|K segs, Q scaled
    const short* __restrict__ VT,   // [64][64][2048]
    short* __restrict__ O)          // [M][1024]
{
    __shared__ short KV[2][2][4096];   // [buf][K/V][64 rows x 64 shorts] = 32KB
    int lin = blockIdx.y * 16 + blockIdx.x;
    int nid = (lin & 7) * 128 + (lin >> 3);
    int bh = nid >> 4, qt = nid & 15;
    int b = bh >> 4, h = bh & 15;
    int q0 = qt * 128;
    int tid = threadIdx.x, wave = tid >> 6, lane = tid & 63;
    int l31 = lane & 31, hi = lane >> 5;
    int sw = l31 & 7;                        // read-side XOR swizzle key

    bf16x8 aq[4];
    {
        const short* qp = QKV + (long)(b*S_ + q0 + wave*32 + l31) * QS_ + h*64 + 8*hi;
#pragma unroll
        for (int t = 0; t < 4; t++)
            aq[t] = *(const bf16x8*)(qp + 16*t);
    }
    bf16x8 ones;
#pragma unroll
    for (int i = 0; i < 8; i++) ones[i] = (short)0x3F80;

    f32x16 accO[2] = {};           // O[qrow=crow(r,hi)][e=32eb+l31]
    f32x16 accsum = {};            // row sums (all cols equal)
    float negmj = 0.0f;            // -(running max), exp2 domain

    int srow = lane >> 3;                    // 0..7
    int schunk = (lane & 7) ^ srow;          // 16B chunk index
    const short* ksrc = QKV + (long)(b*S_ + wave*16 + srow) * QS_ + 1024 + h*64 + schunk*8;
    const short* vsrc = VT + (long)bh * (64L*S_) + (long)(wave*16 + srow) * S_ + schunk*8;
    short* kd = &KV[0][0][wave*1024];
    short* vd = &KV[0][1][wave*1024];

    #define STAGE(buf, kb_) do {                                        \
        gld_lds16(ksrc + (long)(kb_)     * QS_, kd + (buf)*8192);        \
        gld_lds16(ksrc + (long)((kb_)+8) * QS_, kd + (buf)*8192 + 512);  \
        gld_lds16(vsrc + (kb_),                 vd + (buf)*8192);        \
        gld_lds16(vsrc + 8*S_ + (kb_),          vd + (buf)*8192 + 512);  \
    } while (0)

    STAGE(0, 0);
    __syncthreads();

    for (int t = 0; t < 32; ++t) {
        int cur = t & 1;
        if (t < 31) STAGE(cur ^ 1, (t + 1) * 64);
        const char* KB = (const char*)&KV[cur][0][0];
        const char* VB = (const char*)&KV[cur][1][0];

        // ---- QK^T with C-init = -mj: accs = s - mj after MFMA ----
        f32x16 accs[2];
#pragma unroll
        for (int c = 0; c < 2; c++)
#pragma unroll
            for (int r = 0; r < 16; r++) accs[c][r] = negmj;
#pragma unroll
        for (int c = 0; c < 2; c++) {
            bf16x8 ak[4];
#pragma unroll
            for (int tt = 0; tt < 4; tt++)
                ak[tt] = *(const bf16x8*)(KB + (32*c + l31)*128 + (((2*tt + hi) ^ sw) << 4));
            __builtin_amdgcn_s_setprio(1);
#pragma unroll
            for (int tt = 0; tt < 4; tt++)
                accs[c] = __builtin_amdgcn_mfma_f32_32x32x16_bf16(
                    ak[tt], aq[tt], accs[c], 0, 0, 0);
            __builtin_amdgcn_s_setprio(0);
        }

        // ---- defer-max guard, every 4th tile only ----
        if ((t & 3) == 0) {
            float mA = fmaxf(accs[0][0], accs[0][1]);
            float mB = fmaxf(accs[1][0], accs[1][1]);
#pragma unroll
            for (int r = 2; r < 16; r += 2) {
                mA = max3f(mA, accs[0][r], accs[0][r+1]);
                mB = max3f(mB, accs[1][r], accs[1][r+1]);
            }
            float m4 = fmaxf(mA, mB);
            if (!__all(m4 <= 8.0f)) {          // rare rescale path
                float m2 = fmaxf(m4, __shfl_xor(m4, 32));
                float d = fmaxf(m2, 0.0f);
                float al = exp2f(-d);
                negmj -= d;
#pragma unroll
                for (int c = 0; c < 2; c++)
#pragma unroll
                    for (int r = 0; r < 16; r++) accs[c][r] -= d;
#pragma unroll
                for (int r = 0; r < 16; r++) {
                    float alr = __shfl(al, (r & 3) + 8 * (r >> 2) + 4 * hi);
                    accO[0][r] *= alr; accO[1][r] *= alr; accsum[r] *= alr;
                }
            }
        }
#pragma unroll
        for (int c = 0; c < 2; c++)
#pragma unroll
            for (int r = 0; r < 16; r++)
                accs[c][r] = exp2f(accs[c][r]);

        // ---- P -> A-frags: 4 cvt_pk + 2 permlane32_swap per 16-key slot ----
        bf16x8 pa[4];
#pragma unroll
        for (int ks = 0; ks < 4; ks++) {
            int c = ks >> 1, o = (ks & 1) * 8;
            unsigned int c0 = cvtpk_bf16(accs[c][o+0], accs[c][o+1]);
            unsigned int c1 = cvtpk_bf16(accs[c][o+2], accs[c][o+3]);
            unsigned int c2 = cvtpk_bf16(accs[c][o+4], accs[c][o+5]);
            unsigned int c3 = cvtpk_bf16(accs[c][o+6], accs[c][o+7]);
            asm("v_permlane32_swap_b32 %0, %1" : "+v"(c0), "+v"(c2));
            asm("v_permlane32_swap_b32 %0, %1" : "+v"(c1), "+v"(c3));
            union { unsigned int u[4]; bf16x8 v; } pk;
            pk.u[0] = c0; pk.u[1] = c1; pk.u[2] = c2; pk.u[3] = c3;
            pa[ks] = pk.v;
        }

        // ---- PV + MFMA row-sum ----
        __builtin_amdgcn_s_setprio(1);
#pragma unroll
        for (int eb = 0; eb < 2; eb++)
#pragma unroll
            for (int ks = 0; ks < 4; ks++) {
                bf16x8 bvf = *(const bf16x8*)(VB + (32*eb + l31)*128 + (((2*ks + hi) ^ sw) << 4));
                accO[eb] = __builtin_amdgcn_mfma_f32_32x32x16_bf16(
                    pa[ks], bvf, accO[eb], 0, 0, 0);
            }
#pragma unroll
        for (int ks = 0; ks < 4; ks++)
            accsum = __builtin_amdgcn_mfma_f32_32x32x16_bf16(
                pa[ks], ones, accsum, 0, 0, 0);
        __builtin_amdgcn_s_setprio(0);

        __syncthreads();
    }
    #undef STAGE

    const short* ob = O + (long)(b*S_) * 1024 + h*64;
#pragma unroll
    for (int r = 0; r < 16; r++) {
        int crow = (r & 3) + 8 * (r >> 2) + 4 * hi;
        float invr = 1.0f / accsum[r];
        int qr = q0 + wave*32 + crow;
#pragma unroll
        for (int eb = 0; eb < 2; eb++)
            ((short*)ob)[(long)qr * 1024 + 32*eb + l31] = f2bf(accO[eb][r] * invr);
    }
}

// ---------------------------------------------------------------------------
// Residual + LayerNorm: O[row] = LN(X[row] + Y[row]) * g + be   (D=1024)
// ---------------------------------------------------------------------------
template<int XF32, int OUTF32>
__global__ __launch_bounds__(256) void ln_k(
    const void* __restrict__ Xv, const short* __restrict__ Y,
    const float* __restrict__ g, const float* __restrict__ be,
    void* __restrict__ Ov)
{
    int row = blockIdx.x, tid = threadIdx.x;
    long base = (long)row * 1024 + tid * 4;
    float a[4];
    if constexpr (XF32) {
        float4 xv = *(const float4*)((const float*)Xv + base);
        a[0] = xv.x; a[1] = xv.y; a[2] = xv.z; a[3] = xv.w;
    } else {
        short4_t xv = *(const short4_t*)((const short*)Xv + base);
#pragma unroll
        for (int j = 0; j < 4; j++) a[j] = bf2f(xv[j]);
    }
    short4_t yv = *(const short4_t*)(Y + base);
    float s = 0.f, s2 = 0.f;
#pragma unroll
    for (int j = 0; j < 4; j++) {
        a[j] += bf2f(yv[j]);
        s += a[j]; s2 += a[j] * a[j];
    }
#pragma unroll
    for (int off = 32; off >= 1; off >>= 1) {
        s  += __shfl_xor(s, off);
        s2 += __shfl_xor(s2, off);
    }
    __shared__ float red[8];
    if ((tid & 63) == 0) { red[(tid >> 6)*2] = s; red[(tid >> 6)*2 + 1] = s2; }
    __syncthreads();
    s  = red[0] + red[2] + red[4] + red[6];
    s2 = red[1] + red[3] + red[5] + red[7];
    float mean = s * (1.0f/1024.0f);
    float var  = s2 * (1.0f/1024.0f) - mean*mean;
    float rstd = rsqrtf(var + 1e-5f);
    float4 gv = *(const float4*)(g  + tid*4);
    float4 bv = *(const float4*)(be + tid*4);
    float r0 = (a[0] - mean) * rstd * gv.x + bv.x;
    float r1 = (a[1] - mean) * rstd * gv.y + bv.y;
    float r2 = (a[2] - mean) * rstd * gv.z + bv.z;
    float r3 = (a[3] - mean) * rstd * gv.w + bv.w;
    if constexpr (OUTF32) {
        *(float4*)((float*)Ov + base) = make_float4(r0, r1, r2, r3);
    } else {
        short4_t ov;
        ov[0] = f2bf(r0); ov[1] = f2bf(r1); ov[2] = f2bf(r2); ov[3] = f2bf(r3);
        *(short4_t*)((short*)Ov + base) = ov;
    }
}

// ---------------------------------------------------------------------------
extern "C" void kernel_launch(void* const* d_in, const int* in_sizes, int n_in,
                              void* d_out, int out_size, void* d_ws, size_t ws_size,
                              hipStream_t stream)
{
    static const int ins[17] = {0,1,2,3,4,5,6,7,8,9,10,11,12,13,14,15,16};
    static const int srt[17] = {16,4,12,2,10,5,13,3,11,0,6,1,7,14,8,15,9};
    const int* IX = (in_sizes[0] == 8388608) ? ins : srt;

    const float* x   = (const float*)d_in[IX[0]];
    const float* Wq  = (const float*)d_in[IX[1]];
    const float* bq  = (const float*)d_in[IX[2]];
    const float* Wk  = (const float*)d_in[IX[3]];
    const float* bk  = (const float*)d_in[IX[4]];
    const float* Wv  = (const float*)d_in[IX[5]];
    const float* bv  = (const float*)d_in[IX[6]];
    const float* Wo  = (const float*)d_in[IX[7]];
    const float* bo  = (const float*)d_in[IX[8]];
    const float* W1  = (const float*)d_in[IX[9]];
    const float* b1  = (const float*)d_in[IX[10]];
    const float* W2  = (const float*)d_in[IX[11]];
    const float* b2  = (const float*)d_in[IX[12]];
    const float* g1  = (const float*)d_in[IX[13]];
    const float* be1 = (const float*)d_in[IX[14]];
    const float* g2  = (const float*)d_in[IX[15]];
    const float* be2 = (const float*)d_in[IX[16]];
    short* ws  = (short*)d_ws;

    // Workspace overlay (short offsets). Peak 125.8 MB.
    short* QKVb = ws + 0L;          // [8192][3072], dead after attn
    short* VTb  = ws + 25165824L;   // [64][64][2048], dead after attn
    short* ctx  = ws + 33554432L;   // [8192][1024], dead after Wo gemm
    short* QKVT = ws + 41943040L;   // [3072][1024], dead after QKV gemm
    short* WoT  = ws + 45088768L;   // [1024][1024], dead after Wo gemm
    short* xb   = ws + 46137344L;   // [8192][1024], dead after QKV gemm
    short* W1T  = ws + 54525952L;   // [4096][1024]
    short* W2T  = ws + 58720256L;   // [1024][4096]
    short* x1   = ws + 0L;          // reuses QKVb head (dead)
    short* hb   = ws + 8388608L;    // [8192][4096] reuses QKVb tail+VTb+ctx (dead)
    short* ao   = ws + 46137344L;   // reuses xb (dead)
    short* ffn  = ws + 41943040L;   // reuses QKVT+WoT (dead by FFN2)

    dim3 blk(256);

    cvt_f2b_k<<<2048, blk, 0, stream>>>(x, xb, (long)M_ * D_);

    // weight transposes (fp32 -> bf16), [N][K] k-contiguous
    transpose_k<float><<<dim3(2, 32, 16),  blk, 0, stream>>>(Wq, QKVT,            1024, 64,   0, 65536, 65536);
    transpose_k<float><<<dim3(2, 32, 16),  blk, 0, stream>>>(Wk, QKVT + 1048576L, 1024, 64,   0, 65536, 65536);
    transpose_k<float><<<dim3(2, 32, 16),  blk, 0, stream>>>(Wv, QKVT + 2097152L, 1024, 64,   0, 65536, 65536);
    transpose_k<float><<<dim3(32, 32, 1),  blk, 0, stream>>>(Wo, WoT, 1024, 1024, 0, 0, 0);
    transpose_k<float><<<dim3(128, 32, 1), blk, 0, stream>>>(W1, W1T, 1024, 4096, 0, 0, 0);
    transpose_k<float><<<dim3(32, 128, 1), blk, 0, stream>>>(W2, W2T, 4096, 1024, 0, 0, 0);

    // fused QKV projection, 256^2 counted-vmcnt kernel (V written transposed);
    // Q folds 0.125*log2(e) for exp2-domain softmax
    gemm256_k<1><<<dim3(12, 32), dim3(512), 0, stream>>>(
        xb, QKVT, bq, bk, bv, QKVb, VTb, M_, QS_, 1024, 0.18033688011112042f, 0);

    // flash attention
    attn_k<<<dim3(16, 64), blk, 0, stream>>>(QKVb, VTb, ctx);

    // out projection + residual LN (residual from ORIGINAL fp32 x)
    gemm_k<<<dim3(8, 64), blk, 0, stream>>>(ctx, WoT, bo, ao, M_, 1024, 1024, 1.0f, 0);
    ln_k<1,0><<<8192, blk, 0, stream>>>(x, ao, g1, be1, x1);

    // FFN1 on the 256^2 counted-vmcnt kernel (relu fused)
    gemm256_k<0><<<dim3(16, 32), dim3(512), 0, stream>>>(
        x1, W1T, b1, nullptr, nullptr, hb, nullptr, M_, 4096, 1024, 1.0f, 1);
    gemm_k<<<dim3(8, 64),  blk, 0, stream>>>(hb, W2T, b2, ffn, M_, 1024, 4096, 1.0f, 0);

    ln_k<0,1><<<8192, blk, 0, stream>>>(x1, ffn, g2, be2, d_out);
}